// Round 1
// baseline (284.053 us; speedup 1.0000x reference)
//
#include <hip/hip_runtime.h>

// LLR denoiser, restructured:
//   M' = M - THS * G^{-1/2} M   (all singular values >> THS for N(0,1) input)
//   out = x + (sum_patches of -alpha * Z * M) / cnt,  Z ~= (G/f)^{-1/2}, alpha = THS/sqrt(f)
// Newton-Schulz on symmetric 16x16 matrices entirely in MFMA C-layout registers
// (symmetry makes C-layout == A/B-frag layout; no LDS, no barriers needed).

#define NBATCH  2
#define NCH     16
#define HDIM    512
#define WDIM    512
#define PATCH   8
#define PSTRIDE 4
#define NPH     127
#define NPW     127
#define THS     0.1f
#define NSIT    11

typedef short bf16x8 __attribute__((ext_vector_type(8)));
typedef float f32x4  __attribute__((ext_vector_type(4)));

#define MFMA(a,b,c) __builtin_amdgcn_mfma_f32_16x16x32_bf16((a),(b),(c),0,0,0)

static __device__ inline short f2bf(float x) {
  // round-to-nearest-even f32 -> bf16 (inputs finite)
  unsigned int b = __builtin_bit_cast(unsigned int, x);
  unsigned int lsb = (b >> 16) & 1u;
  b += 0x7fffu + lsb;
  return (short)(b >> 16);
}

static __device__ inline bf16x8 fragc(f32x4 v) {
  // symmetric-matrix C-layout -> MFMA A/B fragment (K=16, upper half zero)
  bf16x8 r;
  r[0] = f2bf(v[0]); r[1] = f2bf(v[1]); r[2] = f2bf(v[2]); r[3] = f2bf(v[3]);
  r[4] = 0; r[5] = 0; r[6] = 0; r[7] = 0;
  return r;
}

__global__ __launch_bounds__(64) void llr_patch(const float* __restrict__ x,
                                                float* __restrict__ acc) {
  const int pid = blockIdx.x;                  // one wave per patch
  const int bi  = pid / (NPH * NPW);
  const int pr  = pid % (NPH * NPW);
  const int ph  = pr / NPW, pw = pr % NPW;
  const int h0  = ph * PSTRIDE, w0 = pw * PSTRIDE;
  const int l   = threadIdx.x;
  const int j   = l & 15;                      // row/col id in 16x16 tiles
  const int u   = l >> 4;                      // k-group 0..3

  const size_t HW = (size_t)HDIM * WDIM;
  const float* xb = x + (size_t)bi * NCH * HW;

  // ---- load M (16 channels x 64 pixels) in A-frag layout:
  // lane (u,j): channel j, pixel groups {4u..4u+3}, {16+4u..}, {32+4u..}, {48+4u..}
  const float* pb = xb + (size_t)j * HW + (size_t)h0 * WDIM + w0;
  const int dh0 = (u >> 1), dw0 = 4 * (u & 1);
  float4 q0 = *(const float4*)(pb + (size_t)(dh0 + 0) * WDIM + dw0);
  float4 q1 = *(const float4*)(pb + (size_t)(dh0 + 2) * WDIM + dw0);
  float4 q2 = *(const float4*)(pb + (size_t)(dh0 + 4) * WDIM + dw0);
  float4 q3 = *(const float4*)(pb + (size_t)(dh0 + 6) * WDIM + dw0);

  bf16x8 m0, m1;
  m0[0]=f2bf(q0.x); m0[1]=f2bf(q0.y); m0[2]=f2bf(q0.z); m0[3]=f2bf(q0.w);
  m0[4]=f2bf(q1.x); m0[5]=f2bf(q1.y); m0[6]=f2bf(q1.z); m0[7]=f2bf(q1.w);
  m1[0]=f2bf(q2.x); m1[1]=f2bf(q2.y); m1[2]=f2bf(q2.z); m1[3]=f2bf(q2.w);
  m1[4]=f2bf(q3.x); m1[5]=f2bf(q3.y); m1[6]=f2bf(q3.z); m1[7]=f2bf(q3.w);

  // ---- G = M M^T (same regs as A and B operand: B-frag of M^T == A-frag of M)
  f32x4 g = {0.f, 0.f, 0.f, 0.f};
  g = MFMA(m0, m0, g);
  g = MFMA(m1, m1, g);

  // ---- Frobenius norm^2 of G (wave butterfly reduce)
  float s2 = g[0]*g[0] + g[1]*g[1] + g[2]*g[2] + g[3]*g[3];
  #pragma unroll
  for (int m = 32; m >= 1; m >>= 1) s2 += __shfl_xor(s2, m, 64);

  if (!(s2 > 1e-12f)) return;                  // all-zero patch: zero correction

  const float invf  = rsqrtf(s2);              // 1/f, f = ||G||_F
  const float alpha = THS * sqrtf(invf);       // THS / sqrt(f)

  // ---- coupled Newton-Schulz: Y0 = G/f, Z0 = I; Z -> (G/f)^{-1/2}
  f32x4 Yc, Zc;
  #pragma unroll
  for (int r = 0; r < 4; ++r) {
    Yc[r] = g[r] * invf;
    Zc[r] = (4 * u + r == j) ? 1.0f : 0.0f;
  }

  const f32x4 zero = {0.f, 0.f, 0.f, 0.f};
  for (int it = 0; it < NSIT - 1; ++it) {
    bf16x8 yF = fragc(Yc), zF = fragc(Zc);
    f32x4 t  = MFMA(zF, yF, zero);             // T = Z*Y
    bf16x8 tF = fragc(t);
    f32x4 py = MFMA(yF, tF, zero);             // Y*T
    f32x4 pz = MFMA(tF, zF, zero);             // T*Z
    #pragma unroll
    for (int r = 0; r < 4; ++r) {
      Yc[r] = 1.5f * Yc[r] - 0.5f * py[r];
      Zc[r] = 1.5f * Zc[r] - 0.5f * pz[r];
    }
  }
  { // final iteration: only Z needed
    bf16x8 yF = fragc(Yc), zF = fragc(Zc);
    f32x4 t  = MFMA(zF, yF, zero);
    bf16x8 tF = fragc(t);
    f32x4 pz = MFMA(tF, zF, zero);
    #pragma unroll
    for (int r = 0; r < 4; ++r) Zc[r] = 1.5f * Zc[r] - 0.5f * pz[r];
  }

  // ---- correction R = Z * M (four 16-pixel column blocks), scatter -alpha*R
  bf16x8 zF = fragc(Zc);
  const int dh = (j >> 3), dw = (j & 7);
  #pragma unroll
  for (int bc = 0; bc < 4; ++bc) {
    const int ph2 = 2 * bc + dh;               // pixel p = 16*bc + j
    const float* bb = xb + (size_t)(4 * u) * HW + (size_t)(h0 + ph2) * WDIM + (w0 + dw);
    bf16x8 mB;                                 // B-frag of M: B[4u+e][p], e=0..3
    mB[0] = f2bf(bb[0]);
    mB[1] = f2bf(bb[HW]);
    mB[2] = f2bf(bb[2 * HW]);
    mB[3] = f2bf(bb[3 * HW]);
    mB[4] = 0; mB[5] = 0; mB[6] = 0; mB[7] = 0;
    f32x4 rr = MFMA(zF, mB, zero);             // rr[r] = R[4u+r][p]
    float* ob = acc + ((size_t)bi * NCH + 4 * u) * HW + (size_t)(h0 + ph2) * WDIM + (w0 + dw);
    #pragma unroll
    for (int r = 0; r < 4; ++r) atomicAdd(ob + (size_t)r * HW, -alpha * rr[r]);
  }
}

static __device__ inline float cnt1f(int t) {
  int lo = t - (PATCH - 1); if (lo < 0) lo = 0;
  lo = (lo + PSTRIDE - 1) >> 2;
  int hi = t; if (hi > (HDIM - PATCH)) hi = HDIM - PATCH;
  hi >>= 2;
  return (float)(hi - lo + 1);
}

__global__ void llr_finalize(const float* __restrict__ x, float* __restrict__ out) {
  const size_t n4 = (size_t)NBATCH * NCH * HDIM * WDIM / 4;
  for (size_t i = blockIdx.x * (size_t)blockDim.x + threadIdx.x; i < n4;
       i += (size_t)gridDim.x * blockDim.x) {
    float4 xv = ((const float4*)x)[i];
    float4 av = ((float4*)out)[i];
    const size_t e0 = i * 4;
    const int w = (int)(e0 % WDIM);
    const int h = (int)((e0 / WDIM) % HDIM);
    const float rh = cnt1f(h);
    float4 o;
    o.x = xv.x + av.x / (rh * cnt1f(w + 0));
    o.y = xv.y + av.y / (rh * cnt1f(w + 1));
    o.z = xv.z + av.z / (rh * cnt1f(w + 2));
    o.w = xv.w + av.w / (rh * cnt1f(w + 3));
    ((float4*)out)[i] = o;
  }
}

extern "C" void kernel_launch(void* const* d_in, const int* in_sizes, int n_in,
                              void* d_out, int out_size, void* d_ws, size_t ws_size,
                              hipStream_t stream) {
  const float* x = (const float*)d_in[0];
  float* out = (float*)d_out;

  // d_out doubles as the correction accumulator; must start at zero every call
  hipMemsetAsync(out, 0, sizeof(float) * (size_t)out_size, stream);

  const int nblk = NBATCH * NPH * NPW;         // 32258 patches, one wave each
  llr_patch<<<dim3(nblk), dim3(64), 0, stream>>>(x, out);
  llr_finalize<<<dim3(2048), dim3(256), 0, stream>>>(x, out);
}

// Round 2
// 113.268 us; speedup vs baseline: 2.5078x; 2.5078x over previous
//
#include <hip/hip_runtime.h>

// LLR denoiser, two-phase, atomic-free:
//   Phase 1: per patch p, S_p = alpha_p * Zhat_p  (16x16, ~ THS * G^{-1/2}),
//            computed by register-resident Newton-Schulz; stored bf16 to ws.
//   Phase 2: covering-patch set is constant on each 4x4 stride cell, so
//            out[:,px] = x[:,px] - (sum_{p covering cell} S_p) * x[:,px] / cnt
//            -> one 16x16 MFMA per cell, every output written exactly once.

#define NBATCH  2
#define NCH     16
#define HDIM    512
#define WDIM    512
#define NPH     127
#define NPW     127
#define NCELL   128
#define THS     0.1f
#define NSIT    11

typedef short bf16x8 __attribute__((ext_vector_type(8)));
typedef float f32x4  __attribute__((ext_vector_type(4)));

#define MFMA(a,b,c) __builtin_amdgcn_mfma_f32_16x16x32_bf16((a),(b),(c),0,0,0)

static __device__ inline short f2bf(float x) {
  // native bf16 convert (RNE); compiler can pack pairs into v_cvt_pk_bf16_f32
  return __builtin_bit_cast(short, (__bf16)x);
}

static __device__ inline float blo2f(unsigned int v) {
  return __builtin_bit_cast(float, v << 16);
}
static __device__ inline float bhi2f(unsigned int v) {
  return __builtin_bit_cast(float, v & 0xffff0000u);
}

static __device__ inline bf16x8 fragc(f32x4 v) {
  // symmetric-matrix C-layout -> MFMA A/B fragment (16 nonzero k-slots)
  bf16x8 r;
  r[0] = f2bf(v[0]); r[1] = f2bf(v[1]); r[2] = f2bf(v[2]); r[3] = f2bf(v[3]);
  r[4] = 0; r[5] = 0; r[6] = 0; r[7] = 0;
  return r;
}

// ---------------- Phase 1: per-patch scaled inverse-sqrt matrices ----------
__global__ __launch_bounds__(64) void llr_zs(const float* __restrict__ x,
                                             uint2* __restrict__ zs) {
  const int pid = blockIdx.x;                  // one wave per patch
  const int bi  = pid / (NPH * NPW);
  const int pr  = pid % (NPH * NPW);
  const int ph  = pr / NPW, pw = pr % NPW;
  const int h0  = ph * 4, w0 = pw * 4;
  const int l   = threadIdx.x;
  const int j   = l & 15;                      // row/col id in 16x16 tiles
  const int u   = l >> 4;                      // k-group 0..3

  const size_t HW = (size_t)HDIM * WDIM;
  const float* xb = x + (size_t)bi * NCH * HW;

  // load M (16 channels x 64 pixels) in A-frag layout
  const float* pb = xb + (size_t)j * HW + (size_t)h0 * WDIM + w0;
  const int dh0 = (u >> 1), dw0 = 4 * (u & 1);
  float4 q0 = *(const float4*)(pb + (size_t)(dh0 + 0) * WDIM + dw0);
  float4 q1 = *(const float4*)(pb + (size_t)(dh0 + 2) * WDIM + dw0);
  float4 q2 = *(const float4*)(pb + (size_t)(dh0 + 4) * WDIM + dw0);
  float4 q3 = *(const float4*)(pb + (size_t)(dh0 + 6) * WDIM + dw0);

  bf16x8 m0, m1;
  m0[0]=f2bf(q0.x); m0[1]=f2bf(q0.y); m0[2]=f2bf(q0.z); m0[3]=f2bf(q0.w);
  m0[4]=f2bf(q1.x); m0[5]=f2bf(q1.y); m0[6]=f2bf(q1.z); m0[7]=f2bf(q1.w);
  m1[0]=f2bf(q2.x); m1[1]=f2bf(q2.y); m1[2]=f2bf(q2.z); m1[3]=f2bf(q2.w);
  m1[4]=f2bf(q3.x); m1[5]=f2bf(q3.y); m1[6]=f2bf(q3.z); m1[7]=f2bf(q3.w);

  // G = M M^T
  f32x4 g = {0.f, 0.f, 0.f, 0.f};
  g = MFMA(m0, m0, g);
  g = MFMA(m1, m1, g);

  // Frobenius norm^2 of G
  float s2 = g[0]*g[0] + g[1]*g[1] + g[2]*g[2] + g[3]*g[3];
  #pragma unroll
  for (int m = 32; m >= 1; m >>= 1) s2 += __shfl_xor(s2, m, 64);

  uint2 wv = {0u, 0u};
  if (s2 > 1e-20f) {
    const float invf  = rsqrtf(s2);            // 1/f, f = ||G||_F >= lmax
    const float gsc   = 2.0f * invf;           // normalize by t = f/2 (eig in (0,2])
    const float alpha = THS * sqrtf(gsc);      // THS / sqrt(t)

    // coupled Newton-Schulz: Y0 = G/t, Z0 = I; Z -> (G/t)^{-1/2}
    f32x4 Yc, Zc;
    #pragma unroll
    for (int r = 0; r < 4; ++r) {
      Yc[r] = g[r] * gsc;
      Zc[r] = (4 * u + r == j) ? 1.0f : 0.0f;
    }

    const f32x4 zero = {0.f, 0.f, 0.f, 0.f};
    for (int it = 0; it < NSIT - 1; ++it) {
      bf16x8 yF = fragc(Yc), zF = fragc(Zc);
      f32x4 t  = MFMA(zF, yF, zero);           // T = Z*Y
      bf16x8 tF = fragc(t);
      f32x4 py = MFMA(yF, tF, zero);           // Y*T
      f32x4 pz = MFMA(tF, zF, zero);           // T*Z
      #pragma unroll
      for (int r = 0; r < 4; ++r) {
        Yc[r] = 1.5f * Yc[r] - 0.5f * py[r];
        Zc[r] = 1.5f * Zc[r] - 0.5f * pz[r];
      }
    }
    { // final iteration: only Z needed
      bf16x8 yF = fragc(Yc), zF = fragc(Zc);
      f32x4 t  = MFMA(zF, yF, zero);
      bf16x8 tF = fragc(t);
      f32x4 pz = MFMA(tF, zF, zero);
      #pragma unroll
      for (int r = 0; r < 4; ++r) Zc[r] = 1.5f * Zc[r] - 0.5f * pz[r];
    }

    // pack alpha*Z (C-layout) as 4 bf16
    unsigned int s0 = (unsigned short)f2bf(alpha * Zc[0]);
    unsigned int s1 = (unsigned short)f2bf(alpha * Zc[1]);
    unsigned int s2p = (unsigned short)f2bf(alpha * Zc[2]);
    unsigned int s3 = (unsigned short)f2bf(alpha * Zc[3]);
    wv.x = (s1 << 16) | s0;
    wv.y = (s3 << 16) | s2p;
  }
  zs[(size_t)pid * 64 + l] = wv;               // coalesced 512B per patch
}

// ---------------- Phase 2: per-cell apply out = x - W*x/cnt ----------------
__global__ __launch_bounds__(64) void llr_apply(const float* __restrict__ x,
                                                const uint2* __restrict__ zs,
                                                float* __restrict__ out) {
  const int bid = blockIdx.x;                  // bi*4096 + ci*32 + cq
  const int cq  = bid & 31;
  const int ci  = (bid >> 5) & 127;
  const int bi  = bid >> 12;
  const int l   = threadIdx.x;
  const int j   = l & 15, u = l >> 4;

  const size_t HW = (size_t)HDIM * WDIM;
  const float* xb = x + (size_t)bi * NCH * HW;
  float* ob = out + (size_t)bi * NCH * HW;

  const int hh = 4 * ci + (j >> 2);
  const float cnth = 2.0f - (ci == 0) - (ci == NCELL - 1);
  const f32x4 zero = {0.f, 0.f, 0.f, 0.f};

  #pragma unroll
  for (int c = 0; c < 4; ++c) {
    const int cj = 4 * cq + c;
    const int ww = 4 * cj + (j & 3);

    // W = sum of covering patches' S matrices (same C-layout slot per lane)
    f32x4 W = {0.f, 0.f, 0.f, 0.f};
    #pragma unroll
    for (int a = 0; a < 2; ++a) {
      const int php = ci - 1 + a;
      if ((unsigned)php > (unsigned)(NPH - 1)) continue;
      #pragma unroll
      for (int b2 = 0; b2 < 2; ++b2) {
        const int pwp = cj - 1 + b2;
        if ((unsigned)pwp > (unsigned)(NPW - 1)) continue;
        uint2 z = zs[((size_t)(bi * NPH + php) * NPW + pwp) * 64 + l];
        W[0] += blo2f(z.x); W[1] += bhi2f(z.x);
        W[2] += blo2f(z.y); W[3] += bhi2f(z.y);
      }
    }

    // fragments: A = W (symmetric), B = x[ch 4u+e][px j] for this cell
    const float* px = xb + (size_t)(4 * u) * HW + (size_t)hh * WDIM + ww;
    float xq0 = px[0], xq1 = px[HW], xq2 = px[2 * HW], xq3 = px[3 * HW];

    bf16x8 wF = fragc(W);
    bf16x8 xF;
    xF[0] = f2bf(xq0); xF[1] = f2bf(xq1); xF[2] = f2bf(xq2); xF[3] = f2bf(xq3);
    xF[4] = 0; xF[5] = 0; xF[6] = 0; xF[7] = 0;

    f32x4 d = MFMA(wF, xF, zero);              // d[r] = (W*X)[4u+r][px j]

    const float cntw = 2.0f - (cj == 0) - (cj == NCELL - 1);
    const float s = 1.0f / (cnth * cntw);

    float* po = ob + (size_t)(4 * u) * HW + (size_t)hh * WDIM + ww;
    po[0]      = xq0 - s * d[0];
    po[HW]     = xq1 - s * d[1];
    po[2 * HW] = xq2 - s * d[2];
    po[3 * HW] = xq3 - s * d[3];
  }
}

extern "C" void kernel_launch(void* const* d_in, const int* in_sizes, int n_in,
                              void* d_out, int out_size, void* d_ws, size_t ws_size,
                              hipStream_t stream) {
  const float* x = (const float*)d_in[0];
  float* out = (float*)d_out;
  uint2* zs = (uint2*)d_ws;                    // needs 2*127*127*64*8B = 16.6 MB

  llr_zs<<<dim3(NBATCH * NPH * NPW), dim3(64), 0, stream>>>(x, zs);
  llr_apply<<<dim3(NBATCH * NCELL * (NCELL / 4)), dim3(64), 0, stream>>>(x, zs, out);
}

// Round 3
// 71.609 us; speedup vs baseline: 3.9667x; 1.5818x over previous
//
#include <hip/hip_runtime.h>

// LLR denoiser, two-phase, atomic-free:
//   Phase 1 (llr_zs): per patch p, S_p = alpha_p * Zhat_p (16x16 ~ THS*G^{-1/2})
//            via register-resident Newton-Schulz; stored bf16 to ws (C-layout).
//   Phase 2 (llr_apply): per 4x4 stride cell, W = (sum of covering S_p)/cnt;
//            out[:,px] = x[:,px] - W*x[:,px].  Pure-VALU matvec, fully
//            coalesced float4 I/O, W broadcast from LDS.

#define NBATCH  2
#define NCH     16
#define HDIM    512
#define WDIM    512
#define NPH     127
#define NPW     127
#define THS     0.1f
#define NSIT    9

typedef short bf16x8 __attribute__((ext_vector_type(8)));
typedef float f32x4  __attribute__((ext_vector_type(4)));

#define MFMA(a,b,c) __builtin_amdgcn_mfma_f32_16x16x32_bf16((a),(b),(c),0,0,0)

static __device__ inline short f2bf(float x) {
  return __builtin_bit_cast(short, (__bf16)x);   // native RNE convert
}
static __device__ inline float blo2f(unsigned int v) {
  return __builtin_bit_cast(float, v << 16);
}
static __device__ inline float bhi2f(unsigned int v) {
  return __builtin_bit_cast(float, v & 0xffff0000u);
}

static __device__ inline bf16x8 fragc(f32x4 v) {
  // symmetric-matrix C-layout -> MFMA A/B fragment (16 nonzero k-slots)
  bf16x8 r;
  r[0] = f2bf(v[0]); r[1] = f2bf(v[1]); r[2] = f2bf(v[2]); r[3] = f2bf(v[3]);
  r[4] = 0; r[5] = 0; r[6] = 0; r[7] = 0;
  return r;
}

// ---------------- Phase 1: per-patch scaled inverse-sqrt matrices ----------
__global__ __launch_bounds__(64) void llr_zs(const float* __restrict__ x,
                                             uint2* __restrict__ zs) {
  const int pid = blockIdx.x;                  // one wave per patch
  const int bi  = pid / (NPH * NPW);
  const int pr  = pid % (NPH * NPW);
  const int ph  = pr / NPW, pw = pr % NPW;
  const int h0  = ph * 4, w0 = pw * 4;
  const int l   = threadIdx.x;
  const int j   = l & 15;                      // row/col id in 16x16 tiles
  const int u   = l >> 4;                      // k-group 0..3

  const size_t HW = (size_t)HDIM * WDIM;
  const float* xb = x + (size_t)bi * NCH * HW;

  // load M (16 channels x 64 pixels) in A-frag layout
  const float* pb = xb + (size_t)j * HW + (size_t)h0 * WDIM + w0;
  const int dh0 = (u >> 1), dw0 = 4 * (u & 1);
  float4 q0 = *(const float4*)(pb + (size_t)(dh0 + 0) * WDIM + dw0);
  float4 q1 = *(const float4*)(pb + (size_t)(dh0 + 2) * WDIM + dw0);
  float4 q2 = *(const float4*)(pb + (size_t)(dh0 + 4) * WDIM + dw0);
  float4 q3 = *(const float4*)(pb + (size_t)(dh0 + 6) * WDIM + dw0);

  bf16x8 m0, m1;
  m0[0]=f2bf(q0.x); m0[1]=f2bf(q0.y); m0[2]=f2bf(q0.z); m0[3]=f2bf(q0.w);
  m0[4]=f2bf(q1.x); m0[5]=f2bf(q1.y); m0[6]=f2bf(q1.z); m0[7]=f2bf(q1.w);
  m1[0]=f2bf(q2.x); m1[1]=f2bf(q2.y); m1[2]=f2bf(q2.z); m1[3]=f2bf(q2.w);
  m1[4]=f2bf(q3.x); m1[5]=f2bf(q3.y); m1[6]=f2bf(q3.z); m1[7]=f2bf(q3.w);

  // G = M M^T
  f32x4 g = {0.f, 0.f, 0.f, 0.f};
  g = MFMA(m0, m0, g);
  g = MFMA(m1, m1, g);

  // Frobenius norm^2 of G
  float s2 = g[0]*g[0] + g[1]*g[1] + g[2]*g[2] + g[3]*g[3];
  #pragma unroll
  for (int m = 32; m >= 1; m >>= 1) s2 += __shfl_xor(s2, m, 64);

  uint2 wv = {0u, 0u};
  if (s2 > 1e-20f) {
    const float invf  = rsqrtf(s2);            // 1/f, f = ||G||_F >= lmax
    const float gsc   = 2.0f * invf;           // normalize by t = f/2 (eig in (0,2])
    const float alpha = THS * sqrtf(gsc);      // THS / sqrt(t)

    // coupled Newton-Schulz: Y0 = G/t, Z0 = I; Z -> (G/t)^{-1/2}
    f32x4 Yc, Zc;
    #pragma unroll
    for (int r = 0; r < 4; ++r) {
      Yc[r] = g[r] * gsc;
      Zc[r] = (4 * u + r == j) ? 1.0f : 0.0f;
    }

    const f32x4 zero = {0.f, 0.f, 0.f, 0.f};
    for (int it = 0; it < NSIT - 1; ++it) {
      bf16x8 yF = fragc(Yc), zF = fragc(Zc);
      f32x4 t  = MFMA(zF, yF, zero);           // T = Z*Y
      bf16x8 tF = fragc(t);
      f32x4 py = MFMA(yF, tF, zero);           // Y*T
      f32x4 pz = MFMA(tF, zF, zero);           // T*Z
      #pragma unroll
      for (int r = 0; r < 4; ++r) {
        Yc[r] = 1.5f * Yc[r] - 0.5f * py[r];
        Zc[r] = 1.5f * Zc[r] - 0.5f * pz[r];
      }
    }
    { // final iteration: only Z needed
      bf16x8 yF = fragc(Yc), zF = fragc(Zc);
      f32x4 t  = MFMA(zF, yF, zero);
      bf16x8 tF = fragc(t);
      f32x4 pz = MFMA(tF, zF, zero);
      #pragma unroll
      for (int r = 0; r < 4; ++r) Zc[r] = 1.5f * Zc[r] - 0.5f * pz[r];
    }

    // pack alpha*Z (C-layout) as 4 bf16
    unsigned int s0 = (unsigned short)f2bf(alpha * Zc[0]);
    unsigned int s1 = (unsigned short)f2bf(alpha * Zc[1]);
    unsigned int s2p = (unsigned short)f2bf(alpha * Zc[2]);
    unsigned int s3 = (unsigned short)f2bf(alpha * Zc[3]);
    wv.x = (s1 << 16) | s0;
    wv.y = (s3 << 16) | s2p;
  }
  zs[(size_t)pid * 64 + l] = wv;               // coalesced 512B per patch
}

// ---------------- Phase 2: per-cell apply, coalesced VALU matvec -----------
// Block: one cell-row (4 h) x 128 w (32 cells), 128 threads; thread owns one
// float4 (= one cell width, one row). All global I/O is dwordx4 coalesced.
__global__ __launch_bounds__(128) void llr_apply(const float* __restrict__ x,
                                                 const uint2* __restrict__ zs,
                                                 float* __restrict__ out) {
  __shared__ float Wl[32][257];                // [cell][row*16+col], pad vs conflicts

  const int bid = blockIdx.x;                  // bi*512 + ci*4 + wq
  const int wq  = bid & 3;
  const int ci  = (bid >> 2) & 127;
  const int bi  = bid >> 9;
  const int t   = threadIdx.x;

  const size_t HW = (size_t)HDIM * WDIM;
  const float* xb = x + (size_t)bi * NCH * HW;
  float* ob = out + (size_t)bi * NCH * HW;

  // ---- stage 1: W[cell] = (sum of covering S_p) / cnt  -> LDS
  const float cnth = 2.0f - (ci == 0) - (ci == NPH);
  {
    const int l  = t & 63;
    const int u  = l >> 4, j = l & 15;
    const int c0 = t >> 6;                     // 0..1
    #pragma unroll
    for (int i = 0; i < 16; ++i) {
      const int cell = i * 2 + c0;             // 0..31
      const int cj   = wq * 32 + cell;         // global cell col 0..127
      float a0 = 0.f, a1 = 0.f, a2 = 0.f, a3 = 0.f;
      #pragma unroll
      for (int a = 0; a < 2; ++a) {
        const int ph = ci - 1 + a;
        if ((unsigned)ph > (unsigned)(NPH - 1)) continue;
        #pragma unroll
        for (int b = 0; b < 2; ++b) {
          const int pw = cj - 1 + b;
          if ((unsigned)pw > (unsigned)(NPW - 1)) continue;
          uint2 z = zs[((size_t)((bi * NPH + ph) * NPW + pw)) * 64 + l];
          a0 += blo2f(z.x); a1 += bhi2f(z.x);
          a2 += blo2f(z.y); a3 += bhi2f(z.y);
        }
      }
      const float cntw = 2.0f - (cj == 0) - (cj == NPW);
      const float s = 1.0f / (cnth * cntw);
      float* wr = &Wl[cell][u * 64 + j];       // rows 4u+r, col j
      wr[0]  = s * a0;
      wr[16] = s * a1;
      wr[32] = s * a2;
      wr[48] = s * a3;
    }
  }
  __syncthreads();

  // ---- stage 2: out = x - W*x, thread = (row r, cell cl), float4 wide
  const int r  = t >> 5;                       // 0..3
  const int cl = t & 31;                       // 0..31
  const int h  = 4 * ci + r;
  const int w0 = wq * 128 + 4 * cl;

  const float* px = xb + (size_t)h * WDIM + w0;
  float4 xv[16];
  #pragma unroll
  for (int e = 0; e < 16; ++e) xv[e] = *(const float4*)(px + e * HW);

  float* po = ob + (size_t)h * WDIM + w0;
  #pragma unroll
  for (int c = 0; c < 16; ++c) {
    float4 d = {0.f, 0.f, 0.f, 0.f};
    #pragma unroll
    for (int e = 0; e < 16; ++e) {
      const float w = Wl[cl][c * 16 + e];      // bank=cell: conflict-free bcast
      d.x += w * xv[e].x; d.y += w * xv[e].y;
      d.z += w * xv[e].z; d.w += w * xv[e].w;
    }
    float4 o;
    o.x = xv[c].x - d.x; o.y = xv[c].y - d.y;
    o.z = xv[c].z - d.z; o.w = xv[c].w - d.w;
    *(float4*)(po + (size_t)c * HW) = o;
  }
}

extern "C" void kernel_launch(void* const* d_in, const int* in_sizes, int n_in,
                              void* d_out, int out_size, void* d_ws, size_t ws_size,
                              hipStream_t stream) {
  const float* x = (const float*)d_in[0];
  float* out = (float*)d_out;
  uint2* zs = (uint2*)d_ws;                    // 2*127*127*64*8B = 16.5 MB

  llr_zs<<<dim3(NBATCH * NPH * NPW), dim3(64), 0, stream>>>(x, zs);
  llr_apply<<<dim3(NBATCH * (HDIM / 4) * (WDIM / 128)), dim3(128), 0, stream>>>(x, zs, out);
}

// Round 4
// 53.298 us; speedup vs baseline: 5.3296x; 1.3436x over previous
//
#include <hip/hip_runtime.h>

// LLR denoiser, two-phase, atomic-free:
//   Phase 1 (llr_zs): per patch p, S_p = alpha_p * Zhat_p (16x16 ~ THS*G^{-1/2})
//            via register-resident Newton-Schulz; stored bf16 to ws (C-layout).
//   Phase 2 (llr_apply): per 4x4 stride cell, W = (sum of covering S_p)/cnt;
//            out[:,px] = x[:,px] - W*x[:,px].  Pure-VALU matvec, fully
//            coalesced float4 I/O, W broadcast from LDS.
// Both kernels use an XCD-bijective blockIdx swizzle (HW round-robins blocks
// across 8 XCDs; remap so each XCD's private L2 sees a contiguous work chunk).

#define NBATCH  2
#define NCH     16
#define HDIM    512
#define WDIM    512
#define NPH     127
#define NPW     127
#define NPATCH  (NBATCH * NPH * NPW)
#define THS     0.1f
#define NSIT    8

typedef short bf16x8 __attribute__((ext_vector_type(8)));
typedef float f32x4  __attribute__((ext_vector_type(4)));

#define MFMA(a,b,c) __builtin_amdgcn_mfma_f32_16x16x32_bf16((a),(b),(c),0,0,0)

static __device__ inline short f2bf(float x) {
  return __builtin_bit_cast(short, (__bf16)x);   // native RNE convert
}
static __device__ inline float blo2f(unsigned int v) {
  return __builtin_bit_cast(float, v << 16);
}
static __device__ inline float bhi2f(unsigned int v) {
  return __builtin_bit_cast(float, v & 0xffff0000u);
}

// bijective XCD swizzle (m204): HW places block b on XCD b%8; give XCD x the
// contiguous work chunk starting at x's share boundary.
static __device__ inline int xcd_swz(int b, int nwg) {
  const int q = nwg >> 3, r = nwg & 7;
  const int x = b & 7, lo = b >> 3;
  return (x < r ? x * (q + 1) : r * (q + 1) + (x - r) * q) + lo;
}

static __device__ inline bf16x8 fragc(f32x4 v) {
  // symmetric-matrix C-layout -> MFMA A/B fragment (16 nonzero k-slots)
  bf16x8 r;
  r[0] = f2bf(v[0]); r[1] = f2bf(v[1]); r[2] = f2bf(v[2]); r[3] = f2bf(v[3]);
  r[4] = 0; r[5] = 0; r[6] = 0; r[7] = 0;
  return r;
}

// ---------------- Phase 1: per-patch scaled inverse-sqrt matrices ----------
// 256 threads = 4 waves = 4 consecutive patches per block.
#define ZS_NBLK ((NPATCH + 3) / 4)
__global__ __launch_bounds__(256) void llr_zs(const float* __restrict__ x,
                                              uint2* __restrict__ zs) {
  const int blk = xcd_swz(blockIdx.x, ZS_NBLK);
  const int pid = blk * 4 + (threadIdx.x >> 6);  // one wave per patch
  if (pid >= NPATCH) return;
  const int bi  = pid / (NPH * NPW);
  const int pr  = pid % (NPH * NPW);
  const int ph  = pr / NPW, pw = pr % NPW;
  const int h0  = ph * 4, w0 = pw * 4;
  const int l   = threadIdx.x & 63;
  const int j   = l & 15;                      // row/col id in 16x16 tiles
  const int u   = l >> 4;                      // k-group 0..3

  const size_t HW = (size_t)HDIM * WDIM;
  const float* xb = x + (size_t)bi * NCH * HW;

  // load M (16 channels x 64 pixels) in A-frag layout
  const float* pb = xb + (size_t)j * HW + (size_t)h0 * WDIM + w0;
  const int dh0 = (u >> 1), dw0 = 4 * (u & 1);
  float4 q0 = *(const float4*)(pb + (size_t)(dh0 + 0) * WDIM + dw0);
  float4 q1 = *(const float4*)(pb + (size_t)(dh0 + 2) * WDIM + dw0);
  float4 q2 = *(const float4*)(pb + (size_t)(dh0 + 4) * WDIM + dw0);
  float4 q3 = *(const float4*)(pb + (size_t)(dh0 + 6) * WDIM + dw0);

  bf16x8 m0, m1;
  m0[0]=f2bf(q0.x); m0[1]=f2bf(q0.y); m0[2]=f2bf(q0.z); m0[3]=f2bf(q0.w);
  m0[4]=f2bf(q1.x); m0[5]=f2bf(q1.y); m0[6]=f2bf(q1.z); m0[7]=f2bf(q1.w);
  m1[0]=f2bf(q2.x); m1[1]=f2bf(q2.y); m1[2]=f2bf(q2.z); m1[3]=f2bf(q2.w);
  m1[4]=f2bf(q3.x); m1[5]=f2bf(q3.y); m1[6]=f2bf(q3.z); m1[7]=f2bf(q3.w);

  // G = M M^T
  f32x4 g = {0.f, 0.f, 0.f, 0.f};
  g = MFMA(m0, m0, g);
  g = MFMA(m1, m1, g);

  // Frobenius norm^2 of G
  float s2 = g[0]*g[0] + g[1]*g[1] + g[2]*g[2] + g[3]*g[3];
  #pragma unroll
  for (int m = 32; m >= 1; m >>= 1) s2 += __shfl_xor(s2, m, 64);

  uint2 wv = {0u, 0u};
  if (s2 > 1e-20f) {
    const float invf  = rsqrtf(s2);            // 1/f, f = ||G||_F >= lmax
    const float gsc   = 2.0f * invf;           // normalize by t = f/2 (eig in (0,2])
    const float alpha = THS * sqrtf(gsc);      // THS / sqrt(t)

    // coupled Newton-Schulz: Y0 = G/t, Z0 = I; Z -> (G/t)^{-1/2}
    f32x4 Yc, Zc;
    #pragma unroll
    for (int r = 0; r < 4; ++r) {
      Yc[r] = g[r] * gsc;
      Zc[r] = (4 * u + r == j) ? 1.0f : 0.0f;
    }

    const f32x4 zero = {0.f, 0.f, 0.f, 0.f};
    for (int it = 0; it < NSIT - 1; ++it) {
      bf16x8 yF = fragc(Yc), zF = fragc(Zc);
      f32x4 t  = MFMA(zF, yF, zero);           // T = Z*Y
      bf16x8 tF = fragc(t);
      f32x4 py = MFMA(yF, tF, zero);           // Y*T
      f32x4 pz = MFMA(tF, zF, zero);           // T*Z
      #pragma unroll
      for (int r = 0; r < 4; ++r) {
        Yc[r] = 1.5f * Yc[r] - 0.5f * py[r];
        Zc[r] = 1.5f * Zc[r] - 0.5f * pz[r];
      }
    }
    { // final iteration: only Z needed
      bf16x8 yF = fragc(Yc), zF = fragc(Zc);
      f32x4 t  = MFMA(zF, yF, zero);
      bf16x8 tF = fragc(t);
      f32x4 pz = MFMA(tF, zF, zero);
      #pragma unroll
      for (int r = 0; r < 4; ++r) Zc[r] = 1.5f * Zc[r] - 0.5f * pz[r];
    }

    // pack alpha*Z (C-layout) as 4 bf16
    unsigned int s0 = (unsigned short)f2bf(alpha * Zc[0]);
    unsigned int s1 = (unsigned short)f2bf(alpha * Zc[1]);
    unsigned int s2p = (unsigned short)f2bf(alpha * Zc[2]);
    unsigned int s3 = (unsigned short)f2bf(alpha * Zc[3]);
    wv.x = (s1 << 16) | s0;
    wv.y = (s3 << 16) | s2p;
  }
  zs[(size_t)pid * 64 + l] = wv;               // coalesced 512B per patch
}

// ---------------- Phase 2: per-cell apply, coalesced VALU matvec -----------
// Block: one cell-row (4 h) x 128 w (32 cells), 128 threads; thread owns one
// float4 (= one cell width, one row). All global I/O is dwordx4 coalesced.
#define AP_NBLK (NBATCH * (HDIM / 4) * (WDIM / 128))
__global__ __launch_bounds__(128) void llr_apply(const float* __restrict__ x,
                                                 const uint2* __restrict__ zs,
                                                 float* __restrict__ out) {
  __shared__ float Wl[32][257];                // [cell][row*16+col], pad vs conflicts

  const int bid = xcd_swz(blockIdx.x, AP_NBLK); // bi*512 + ci*4 + wq
  const int wq  = bid & 3;
  const int ci  = (bid >> 2) & 127;
  const int bi  = bid >> 9;
  const int t   = threadIdx.x;

  const size_t HW = (size_t)HDIM * WDIM;
  const float* xb = x + (size_t)bi * NCH * HW;
  float* ob = out + (size_t)bi * NCH * HW;

  // ---- stage 1: W[cell] = (sum of covering S_p) / cnt  -> LDS
  const float cnth = 2.0f - (ci == 0) - (ci == NPH);
  {
    const int l  = t & 63;
    const int u  = l >> 4, j = l & 15;
    const int c0 = t >> 6;                     // 0..1
    #pragma unroll
    for (int i = 0; i < 16; ++i) {
      const int cell = i * 2 + c0;             // 0..31
      const int cj   = wq * 32 + cell;         // global cell col 0..127
      float a0 = 0.f, a1 = 0.f, a2 = 0.f, a3 = 0.f;
      #pragma unroll
      for (int a = 0; a < 2; ++a) {
        const int ph = ci - 1 + a;
        if ((unsigned)ph > (unsigned)(NPH - 1)) continue;
        #pragma unroll
        for (int b = 0; b < 2; ++b) {
          const int pw = cj - 1 + b;
          if ((unsigned)pw > (unsigned)(NPW - 1)) continue;
          uint2 z = zs[((size_t)((bi * NPH + ph) * NPW + pw)) * 64 + l];
          a0 += blo2f(z.x); a1 += bhi2f(z.x);
          a2 += blo2f(z.y); a3 += bhi2f(z.y);
        }
      }
      const float cntw = 2.0f - (cj == 0) - (cj == NPW);
      const float s = 1.0f / (cnth * cntw);
      float* wr = &Wl[cell][u * 64 + j];       // rows 4u+r, col j
      wr[0]  = s * a0;
      wr[16] = s * a1;
      wr[32] = s * a2;
      wr[48] = s * a3;
    }
  }
  __syncthreads();

  // ---- stage 2: out = x - W*x, thread = (row r, cell cl), float4 wide
  const int r  = t >> 5;                       // 0..3
  const int cl = t & 31;                       // 0..31
  const int h  = 4 * ci + r;
  const int w0 = wq * 128 + 4 * cl;

  const float* px = xb + (size_t)h * WDIM + w0;
  float4 xv[16];
  #pragma unroll
  for (int e = 0; e < 16; ++e) xv[e] = *(const float4*)(px + e * HW);

  float* po = ob + (size_t)h * WDIM + w0;
  #pragma unroll
  for (int c = 0; c < 16; ++c) {
    float4 d = {0.f, 0.f, 0.f, 0.f};
    #pragma unroll
    for (int e = 0; e < 16; ++e) {
      const float w = Wl[cl][c * 16 + e];      // bank=cell: conflict-free bcast
      d.x += w * xv[e].x; d.y += w * xv[e].y;
      d.z += w * xv[e].z; d.w += w * xv[e].w;
    }
    float4 o;
    o.x = xv[c].x - d.x; o.y = xv[c].y - d.y;
    o.z = xv[c].z - d.z; o.w = xv[c].w - d.w;
    *(float4*)(po + (size_t)c * HW) = o;
  }
}

extern "C" void kernel_launch(void* const* d_in, const int* in_sizes, int n_in,
                              void* d_out, int out_size, void* d_ws, size_t ws_size,
                              hipStream_t stream) {
  const float* x = (const float*)d_in[0];
  float* out = (float*)d_out;
  uint2* zs = (uint2*)d_ws;                    // 32258*512B = 16.5 MB

  llr_zs<<<dim3(ZS_NBLK), dim3(256), 0, stream>>>(x, zs);
  llr_apply<<<dim3(AP_NBLK), dim3(128), 0, stream>>>(x, zs, out);
}

// Round 5
// 50.990 us; speedup vs baseline: 5.5708x; 1.0453x over previous
//
#include <hip/hip_runtime.h>

// LLR denoiser, two-phase, atomic-free:
//   Phase 1 (llr_zs): per patch p, S_p = alpha_p * Zhat_p (16x16 ~ THS*G^{-1/2})
//            via register-resident Newton-Schulz; stored bf16 to ws (C-layout).
//   Phase 2 (llr_apply): per 4x4 stride cell, W = (sum of covering S_p)/cnt;
//            out = x - W*x. One wave per 16 cells: x prefetched to registers,
//            W packed bf16 in LDS (no barrier needed, wave-synchronous).
// Both kernels use an XCD-bijective blockIdx swizzle for L2 locality.

#define NBATCH  2
#define NCH     16
#define HDIM    512
#define WDIM    512
#define NPH     127
#define NPW     127
#define NPATCH  (NBATCH * NPH * NPW)
#define THS     0.1f
#define NSIT    8

typedef short bf16x8 __attribute__((ext_vector_type(8)));
typedef float f32x4  __attribute__((ext_vector_type(4)));

#define MFMA(a,b,c) __builtin_amdgcn_mfma_f32_16x16x32_bf16((a),(b),(c),0,0,0)

static __device__ inline short f2bf(float x) {
  return __builtin_bit_cast(short, (__bf16)x);   // native RNE convert
}
static __device__ inline float blo2f(unsigned int v) {
  return __builtin_bit_cast(float, v << 16);
}
static __device__ inline float bhi2f(unsigned int v) {
  return __builtin_bit_cast(float, v & 0xffff0000u);
}
static __device__ inline unsigned int pack2bf(float lo, float hi) {
  unsigned int a = (unsigned short)f2bf(lo);
  unsigned int b = (unsigned short)f2bf(hi);
  return (b << 16) | a;
}

// bijective XCD swizzle (m204): HW places block b on XCD b%8; give XCD x a
// contiguous chunk of the work range.
static __device__ inline int xcd_swz(int b, int nwg) {
  const int q = nwg >> 3, r = nwg & 7;
  const int x = b & 7, lo = b >> 3;
  return (x < r ? x * (q + 1) : r * (q + 1) + (x - r) * q) + lo;
}

static __device__ inline bf16x8 fragc(f32x4 v) {
  // symmetric-matrix C-layout -> MFMA A/B fragment (16 nonzero k-slots)
  bf16x8 r;
  r[0] = f2bf(v[0]); r[1] = f2bf(v[1]); r[2] = f2bf(v[2]); r[3] = f2bf(v[3]);
  r[4] = 0; r[5] = 0; r[6] = 0; r[7] = 0;
  return r;
}

// ---------------- Phase 1: per-patch scaled inverse-sqrt matrices ----------
// 256 threads = 4 waves = 4 consecutive patches per block.
#define ZS_NBLK ((NPATCH + 3) / 4)
__global__ __launch_bounds__(256) void llr_zs(const float* __restrict__ x,
                                              uint2* __restrict__ zs) {
  const int blk = xcd_swz(blockIdx.x, ZS_NBLK);
  const int pid = blk * 4 + (threadIdx.x >> 6);  // one wave per patch
  if (pid >= NPATCH) return;
  const int bi  = pid / (NPH * NPW);
  const int pr  = pid % (NPH * NPW);
  const int ph  = pr / NPW, pw = pr % NPW;
  const int h0  = ph * 4, w0 = pw * 4;
  const int l   = threadIdx.x & 63;
  const int j   = l & 15;                      // row/col id in 16x16 tiles
  const int u   = l >> 4;                      // k-group 0..3

  const size_t HW = (size_t)HDIM * WDIM;
  const float* xb = x + (size_t)bi * NCH * HW;

  // load M (16 channels x 64 pixels) in A-frag layout
  const float* pb = xb + (size_t)j * HW + (size_t)h0 * WDIM + w0;
  const int dh0 = (u >> 1), dw0 = 4 * (u & 1);
  float4 q0 = *(const float4*)(pb + (size_t)(dh0 + 0) * WDIM + dw0);
  float4 q1 = *(const float4*)(pb + (size_t)(dh0 + 2) * WDIM + dw0);
  float4 q2 = *(const float4*)(pb + (size_t)(dh0 + 4) * WDIM + dw0);
  float4 q3 = *(const float4*)(pb + (size_t)(dh0 + 6) * WDIM + dw0);

  bf16x8 m0, m1;
  m0[0]=f2bf(q0.x); m0[1]=f2bf(q0.y); m0[2]=f2bf(q0.z); m0[3]=f2bf(q0.w);
  m0[4]=f2bf(q1.x); m0[5]=f2bf(q1.y); m0[6]=f2bf(q1.z); m0[7]=f2bf(q1.w);
  m1[0]=f2bf(q2.x); m1[1]=f2bf(q2.y); m1[2]=f2bf(q2.z); m1[3]=f2bf(q2.w);
  m1[4]=f2bf(q3.x); m1[5]=f2bf(q3.y); m1[6]=f2bf(q3.z); m1[7]=f2bf(q3.w);

  // G = M M^T
  f32x4 g = {0.f, 0.f, 0.f, 0.f};
  g = MFMA(m0, m0, g);
  g = MFMA(m1, m1, g);

  // Frobenius norm^2 of G
  float s2 = g[0]*g[0] + g[1]*g[1] + g[2]*g[2] + g[3]*g[3];
  #pragma unroll
  for (int m = 32; m >= 1; m >>= 1) s2 += __shfl_xor(s2, m, 64);

  uint2 wv = {0u, 0u};
  if (s2 > 1e-20f) {
    const float invf  = rsqrtf(s2);            // 1/f, f = ||G||_F >= lmax
    const float gsc   = 2.0f * invf;           // normalize by t = f/2 (eig in (0,2])
    const float alpha = THS * sqrtf(gsc);      // THS / sqrt(t)

    // coupled Newton-Schulz: Y0 = G/t, Z0 = I; Z -> (G/t)^{-1/2}
    f32x4 Yc, Zc;
    #pragma unroll
    for (int r = 0; r < 4; ++r) {
      Yc[r] = g[r] * gsc;
      Zc[r] = (4 * u + r == j) ? 1.0f : 0.0f;
    }

    const f32x4 zero = {0.f, 0.f, 0.f, 0.f};
    for (int it = 0; it < NSIT - 1; ++it) {
      bf16x8 yF = fragc(Yc), zF = fragc(Zc);
      f32x4 t  = MFMA(zF, yF, zero);           // T = Z*Y
      bf16x8 tF = fragc(t);
      f32x4 py = MFMA(yF, tF, zero);           // Y*T
      f32x4 pz = MFMA(tF, zF, zero);           // T*Z
      #pragma unroll
      for (int r = 0; r < 4; ++r) {
        Yc[r] = 1.5f * Yc[r] - 0.5f * py[r];
        Zc[r] = 1.5f * Zc[r] - 0.5f * pz[r];
      }
    }
    { // final iteration: only Z needed
      bf16x8 yF = fragc(Yc), zF = fragc(Zc);
      f32x4 t  = MFMA(zF, yF, zero);
      bf16x8 tF = fragc(t);
      f32x4 pz = MFMA(tF, zF, zero);
      #pragma unroll
      for (int r = 0; r < 4; ++r) Zc[r] = 1.5f * Zc[r] - 0.5f * pz[r];
    }

    wv.x = pack2bf(alpha * Zc[0], alpha * Zc[1]);
    wv.y = pack2bf(alpha * Zc[2], alpha * Zc[3]);
  }
  zs[(size_t)pid * 64 + l] = wv;               // coalesced 512B per patch
}

// ---------------- Phase 2: per-cell apply, 1 wave per 16 cells -------------
// Thread (r, cw): row h=4ci+r, float4 at w = wq*64 + 4cw. x prefetched first
// (HBM latency hides under the zs gather); W packed bf16-pairs in LDS.
#define AP_NBLK (NBATCH * (HDIM / 4) * (WDIM / 64))   // 2048
__global__ __launch_bounds__(64) void llr_apply(const float* __restrict__ x,
                                                const uint2* __restrict__ zs,
                                                float* __restrict__ out) {
  // P[cell][rp*16 + e] = pack(W[2rp][e], W[2rp+1][e]); pad 133 -> bank = 5*cw
  __shared__ unsigned int P[16][133];          // 8.5 KB

  const int bid = xcd_swz(blockIdx.x, AP_NBLK); // bi*1024 + ci*8 + wq
  const int wq  = bid & 7;
  const int ci  = (bid >> 3) & 127;
  const int bi  = bid >> 10;
  const int t   = threadIdx.x;

  const size_t HW = (size_t)HDIM * WDIM;
  const float* xb = x + (size_t)bi * NCH * HW;
  float* ob = out + (size_t)bi * NCH * HW;

  // ---- prefetch x: 16 coalesced dwordx4, in flight during the gather
  const int r  = t >> 4;                       // 0..3 (h row in cell-row)
  const int cw = t & 15;                       // 0..15 (cell in block)
  const int h  = 4 * ci + r;
  const int w0 = wq * 64 + 4 * cw;
  const float* px = xb + (size_t)h * WDIM + w0;
  float4 xv[16];
  #pragma unroll
  for (int e = 0; e < 16; ++e) xv[e] = *(const float4*)(px + e * HW);

  // ---- stage 1: W[cell] = (sum of covering S_p)/cnt -> LDS (packed bf16)
  {
    const int u = t >> 4, j = t & 15;          // zs C-layout lane coords
    const float cnth = 2.0f - (ci == 0) - (ci == NPH);
    #pragma unroll
    for (int i = 0; i < 16; ++i) {
      const int cj = wq * 16 + i;              // global cell col 0..127
      float a0 = 0.f, a1 = 0.f, a2 = 0.f, a3 = 0.f;
      #pragma unroll
      for (int a = 0; a < 2; ++a) {
        const int ph = ci - 1 + a;
        if ((unsigned)ph > (unsigned)(NPH - 1)) continue;
        #pragma unroll
        for (int b = 0; b < 2; ++b) {
          const int pw = cj - 1 + b;
          if ((unsigned)pw > (unsigned)(NPW - 1)) continue;
          uint2 z = zs[((size_t)((bi * NPH + ph) * NPW + pw)) * 64 + t];
          a0 += blo2f(z.x); a1 += bhi2f(z.x);
          a2 += blo2f(z.y); a3 += bhi2f(z.y);
        }
      }
      const float cntw = 2.0f - (cj == 0) - (cj == NPW);
      const float s = 1.0f / (cnth * cntw);
      // lane (u,j) holds rows 4u..4u+3, col j -> row-pairs rp=2u, 2u+1
      P[i][(2 * u) * 16 + j]     = pack2bf(s * a0, s * a1);
      P[i][(2 * u + 1) * 16 + j] = pack2bf(s * a2, s * a3);
    }
  }
  // single wave: no __syncthreads needed (lgkmcnt ordering by compiler)

  // ---- stage 2: out = x - W*x (channel pairs per packed LDS word)
  float* po = ob + (size_t)h * WDIM + w0;
  #pragma unroll
  for (int cp = 0; cp < 8; ++cp) {
    float4 d0 = {0.f, 0.f, 0.f, 0.f};
    float4 d1 = {0.f, 0.f, 0.f, 0.f};
    #pragma unroll
    for (int e = 0; e < 16; ++e) {
      const unsigned int wp = P[cw][cp * 16 + e];
      const float wlo = blo2f(wp), whi = bhi2f(wp);
      d0.x += wlo * xv[e].x; d0.y += wlo * xv[e].y;
      d0.z += wlo * xv[e].z; d0.w += wlo * xv[e].w;
      d1.x += whi * xv[e].x; d1.y += whi * xv[e].y;
      d1.z += whi * xv[e].z; d1.w += whi * xv[e].w;
    }
    const int c0 = 2 * cp, c1 = 2 * cp + 1;
    float4 o0, o1;
    o0.x = xv[c0].x - d0.x; o0.y = xv[c0].y - d0.y;
    o0.z = xv[c0].z - d0.z; o0.w = xv[c0].w - d0.w;
    o1.x = xv[c1].x - d1.x; o1.y = xv[c1].y - d1.y;
    o1.z = xv[c1].z - d1.z; o1.w = xv[c1].w - d1.w;
    *(float4*)(po + (size_t)c0 * HW) = o0;
    *(float4*)(po + (size_t)c1 * HW) = o1;
  }
}

extern "C" void kernel_launch(void* const* d_in, const int* in_sizes, int n_in,
                              void* d_out, int out_size, void* d_ws, size_t ws_size,
                              hipStream_t stream) {
  const float* x = (const float*)d_in[0];
  float* out = (float*)d_out;
  uint2* zs = (uint2*)d_ws;                    // 32258*512B = 16.5 MB

  llr_zs<<<dim3(ZS_NBLK), dim3(256), 0, stream>>>(x, zs);
  llr_apply<<<dim3(AP_NBLK), dim3(64), 0, stream>>>(x, zs, out);
}